// Round 5
// baseline (300.346 us; speedup 1.0000x reference)
//
#include <hip/hip_runtime.h>
#include <hip/hip_bf16.h>

#define B_ 4
#define L_ 4096
#define D_ 2048
#define H_ 128
#define M_ (B_ * L_)  // 16384

typedef __attribute__((ext_vector_type(8))) short bf16x8;
typedef __attribute__((ext_vector_type(4))) float f32x4;
typedef __attribute__((ext_vector_type(16))) float f32x16;

__device__ __forceinline__ unsigned short f2bf(float f) {
  union { float f; unsigned u; } v; v.f = f;
  unsigned r = v.u + 0x7FFFu + ((v.u >> 16) & 1u);
  return (unsigned short)(r >> 16);
}

__device__ __forceinline__ unsigned cvt_pk_bf16(float lo, float hi) {
  unsigned r;
  asm("v_cvt_pk_bf16_f32 %0, %1, %2" : "=v"(r) : "v"(lo), "v"(hi));
  return r;
}

__device__ __forceinline__ void async_copy16(void* lds, const void* gptr) {
  __builtin_amdgcn_global_load_lds(
      (const __attribute__((address_space(1))) unsigned int*)gptr,
      (__attribute__((address_space(3))) unsigned int*)lds, 16, 0, 0);
}

// ---------------------------------------------------------------------------
// Weight convert: Wt row R = 96*(n>>5) + 32*mat + (n&31), cols = d (bf16).
// 1/sqrt(128) folded into Wq.
// ---------------------------------------------------------------------------
__global__ void wconv(const float* __restrict__ Wq, const float* __restrict__ Wk,
                      const float* __restrict__ Wv, unsigned short* __restrict__ Wt) {
  int i = blockIdx.x * 256 + threadIdx.x;  // 3*128*2048
  int m = i >> 18;
  int rem = i & 262143;
  int n = rem >> 11;
  int d = rem & 2047;
  const float* W = (m == 0) ? Wq : (m == 1 ? Wk : Wv);
  float val = W[(size_t)d * H_ + n];
  if (m == 0) val *= 0.08838834764831845f;
  int R = 96 * (n >> 5) + 32 * m + (n & 31);
  Wt[(size_t)R * D_ + d] = f2bf(val);
}

// ---------------------------------------------------------------------------
// Fused QKV GEMM: x[16384,2048]fp32 @ Wt^T -> q,k [B*L][H] bf16, vt [B][H][L].
// BM=64, BN=384, BK=32, 512 thr (8 waves), double-buffered 64 KB LDS =>
// 2 blocks/CU; counted s_waitcnt vmcnt(4) (T4) - never drains to 0 in loop.
// ---------------------------------------------------------------------------
__global__ __launch_bounds__(512, 4) void qkv_gemm(
    const float* __restrict__ x, const unsigned short* __restrict__ Wt,
    unsigned short* __restrict__ qo, unsigned short* __restrict__ ko,
    unsigned short* __restrict__ vt) {
  __shared__ __align__(16) char Ab[2][8192];   // fp32 A [64 r][128 B] swizzled
  __shared__ __align__(16) char Bb[2][24576];  // bf16 B [384 r][64 B] swizzled

  int tid = threadIdx.x;
  int row0 = blockIdx.x * 64;
  int lane = tid & 63, w = tid >> 6;
  int wrow = (w >> 2) * 32;
  int g = w & 3;
  int l15 = lane & 15, lhi = lane >> 4;

  f32x4 zero = {0.f, 0.f, 0.f, 0.f};
  f32x4 acc[2][6];
#pragma unroll
  for (int i = 0; i < 2; i++)
#pragma unroll
    for (int j = 0; j < 6; j++) acc[i][j] = zero;

  const char* xg = (const char*)x;
  const char* wg = (const char*)Wt;

  // stage one 32-wide K-slice into buffer bi (A: 1 load/thr, B: 3 loads/thr)
#define QSTAGE(bi, k0)                                                         \
  {                                                                            \
    {                                                                          \
      int o = tid * 16;                                                        \
      int r = o >> 7;                                                          \
      int cb = (o & 127) ^ ((r & 7) << 4);                                     \
      async_copy16(Ab[bi] + o, xg + (((size_t)(row0 + r) * D_ + (k0)) << 2) + cb); \
    }                                                                          \
    _Pragma("unroll") for (int p = 0; p < 3; p++) {                            \
      int o = (p * 512 + tid) * 16;                                            \
      int r = o >> 6;                                                          \
      int cb = (o & 63) ^ ((r & 3) << 4);                                      \
      async_copy16(Bb[bi] + o, wg + (((size_t)r * D_ + (k0)) << 1) + cb);      \
    }                                                                          \
  }

  QSTAGE(0, 0);

  for (int t = 0; t < 64; t++) {
    int buf = t & 1;
    if (t < 63) {
      QSTAGE(buf ^ 1, (t + 1) * 32);
      // wait for OUR previous tile's 4 loads only; keep next 4 in flight (T4)
      asm volatile("s_waitcnt vmcnt(4)" ::: "memory");
    } else {
      asm volatile("s_waitcnt vmcnt(0)" ::: "memory");
    }
    __builtin_amdgcn_s_barrier();

    const char* A = Ab[buf];
    const char* Bp = Bb[buf];
    bf16x8 af[2], bfr[6];
#pragma unroll
    for (int mi = 0; mi < 2; mi++) {
      int r = wrow + mi * 16 + l15;
      int sw = (r & 7) << 4;
      int cb = lhi * 32;
      float4 lo = *(const float4*)(A + r * 128 + (cb ^ sw));
      float4 hi = *(const float4*)(A + r * 128 + ((cb + 16) ^ sw));
      union { bf16x8 v; unsigned u[4]; } tt;
      tt.u[0] = cvt_pk_bf16(lo.x, lo.y);
      tt.u[1] = cvt_pk_bf16(lo.z, lo.w);
      tt.u[2] = cvt_pk_bf16(hi.x, hi.y);
      tt.u[3] = cvt_pk_bf16(hi.z, hi.w);
      af[mi] = tt.v;
    }
#pragma unroll
    for (int ni = 0; ni < 6; ni++) {
      int r = g * 96 + ni * 16 + l15;
      int sw = (r & 3) << 4;
      int cb = lhi * 16;
      bfr[ni] = *(const bf16x8*)(Bp + r * 64 + (cb ^ sw));
    }
#pragma unroll
    for (int mi = 0; mi < 2; mi++)
#pragma unroll
      for (int ni = 0; ni < 6; ni++)
        acc[mi][ni] = __builtin_amdgcn_mfma_f32_16x16x32_bf16(af[mi], bfr[ni], acc[mi][ni], 0, 0, 0);

    // all ds_reads are retired by the MFMAs' lgkmcnt waits before this point
    asm volatile("" ::: "memory");
    __builtin_amdgcn_s_barrier();
  }
#undef QSTAGE

#pragma unroll
  for (int ni = 0; ni < 4; ni++) {
    unsigned short* dst = (ni < 2) ? qo : ko;
    int nn = 32 * g + (ni & 1) * 16 + l15;
#pragma unroll
    for (int mi = 0; mi < 2; mi++)
#pragma unroll
      for (int r = 0; r < 4; r++) {
        int m = row0 + wrow + mi * 16 + lhi * 4 + r;
        dst[(size_t)m * H_ + nn] = f2bf(acc[mi][ni][r]);
      }
  }
  // V: transpose 32x32 per-wave tile via private LDS slice (in Bb, per-wave)
  unsigned short* Tls = (unsigned short*)(Bb[0]) + w * 1280;  // [32][40]
#pragma unroll
  for (int ni = 4; ni < 6; ni++)
#pragma unroll
    for (int mi = 0; mi < 2; mi++)
#pragma unroll
      for (int r = 0; r < 4; r++)
        Tls[((ni - 4) * 16 + l15) * 40 + mi * 16 + lhi * 4 + r] = f2bf(acc[mi][ni][r]);
  {
    int b = row0 >> 12;
    int Lbase = (row0 & 4095) + wrow;
    int n_loc = lane >> 1;
    int half = (lane & 1) * 16;
    int h = 32 * g + n_loc;
#pragma unroll
    for (int j = 0; j < 2; j++) {
      bf16x8 v = *(const bf16x8*)&Tls[n_loc * 40 + half + j * 8];
      *(bf16x8*)&vt[(((size_t)(b * H_ + h)) << 12) + Lbase + half + j * 8] = v;
    }
  }
}

// ---------------------------------------------------------------------------
// Flash attention partials. Block = 128 q-rows (4 waves x 32) x 1024-key
// chunk; K/V tiles (64 keys) double-buffered in LDS, shared by all 4 waves.
// Swapped QK^T (32x32 MFMA), in-register softmax.
// Grid 320: (80 heavy-first (j,c) pairs) x 4 batches.
// ---------------------------------------------------------------------------
__global__ __launch_bounds__(256, 2) void attn(
    const unsigned short* __restrict__ q, const unsigned short* __restrict__ k,
    const unsigned short* __restrict__ vt, float* __restrict__ po,
    float* __restrict__ pm, float* __restrict__ pl) {
  __shared__ __align__(16) char Kb[2][16384];  // K tile [64 keys][128 d] bf16, swizzled
  __shared__ __align__(16) char Vb[2][16384];  // V^T tile [128 h][64 keys] bf16, swizzled

  int bid = blockIdx.x;
  int b = bid & 3;
  int p2 = bid >> 2;  // 0..79, heavy-first
  int j, c;
  if (p2 < 32)      { j = 31 - (p2 >> 2);            c = p2 & 3; }
  else if (p2 < 56) { int i = p2 - 32; int d3 = i / 3; j = 23 - d3; c = i - 3 * d3; }
  else if (p2 < 72) { int i = p2 - 56; j = 15 - (i >> 1); c = i & 1; }
  else              { j = 7 - (p2 - 72);             c = 0; }

  int kbase = c << 10;
  int kmax = min((c + 1) << 10, (j + 1) << 7);
  int NT = (kmax - kbase) >> 6;

  int tid = threadIdx.x;
  int w = tid >> 6, lane = tid & 63;
  int q31 = lane & 31, hi = lane >> 5;
  int qw0 = (j << 7) + (w << 5);  // this wave's 32 q-rows
  int kcap = qw0 + 32;

  const unsigned short* qb = q + ((size_t)b << 12) * H_;
  const char* kbyte = (const char*)(k + ((size_t)b << 12) * H_);
  const char* vbyte = (const char*)(vt + ((size_t)b * H_ << 12));

  bf16x8 qf[8];
#pragma unroll
  for (int kk = 0; kk < 8; kk++)
    qf[kk] = *(const bf16x8*)&qb[(size_t)(qw0 + q31) * H_ + kk * 16 + hi * 8];

  f32x16 o[4];
#pragma unroll
  for (int hb = 0; hb < 4; hb++)
#pragma unroll
    for (int r = 0; r < 16; r++) o[hb][r] = 0.f;
  float mrun = -1e30f, lrun = 0.f;

  int ksw = (q31 & 7) << 4;

#define STAGE(bi, k0)                                                          \
  {                                                                            \
    _Pragma("unroll") for (int p = 0; p < 4; p++) {                            \
      int oo = (p * 256 + tid) * 16;                                           \
      int rr = oo >> 8;                                                        \
      int cc = (oo & 255) ^ ((rr & 7) << 4);                                   \
      async_copy16(Kb[bi] + oo, kbyte + (size_t)((k0) + rr) * 256 + cc);       \
    }                                                                          \
    _Pragma("unroll") for (int p = 0; p < 4; p++) {                            \
      int oo = (p * 256 + tid) * 16;                                           \
      int hh = oo >> 7;                                                        \
      int cc = (oo & 127) ^ ((hh & 7) << 4);                                   \
      async_copy16(Vb[bi] + oo, vbyte + (size_t)hh * 8192 + (size_t)(k0) * 2 + cc); \
    }                                                                          \
  }

  STAGE(0, kbase);

  for (int t = 0; t < NT; t++) {
    __syncthreads();  // drains vmcnt(0): buf[t&1] staged; prior ds_reads done
    int k0 = kbase + (t << 6);
    if (t + 1 < NT) STAGE((t + 1) & 1, k0 + 64);
    const char* Kc = Kb[t & 1];
    const char* Vc = Vb[t & 1];

#pragma unroll
    for (int sub = 0; sub < 2; sub++) {
      int k0s = k0 + (sub << 5);
      if (k0s < kcap) {
        int kloc2 = sub << 5;
        const char* Krow = Kc + (kloc2 + q31) * 256;
        f32x16 s;
#pragma unroll
        for (int r = 0; r < 16; r++) s[r] = 0.f;
#pragma unroll
        for (int kk = 0; kk < 8; kk++) {
          bf16x8 kf = *(const bf16x8*)(Krow + ((kk * 32 + hi * 16) ^ ksw));
          s = __builtin_amdgcn_mfma_f32_32x32x16_bf16(kf, qf[kk], s, 0, 0, 0);
        }
        if (k0s == qw0) {
#pragma unroll
          for (int r = 0; r < 16; r++) {
            int kloc = (r & 3) + 8 * (r >> 2) + 4 * hi;
            if (kloc > q31) s[r] = -1e30f;
          }
        }
        float m0 = fmaxf(fmaxf(s[0], s[1]), fmaxf(s[2], s[3]));
        float m1 = fmaxf(fmaxf(s[4], s[5]), fmaxf(s[6], s[7]));
        float m2 = fmaxf(fmaxf(s[8], s[9]), fmaxf(s[10], s[11]));
        float m3 = fmaxf(fmaxf(s[12], s[13]), fmaxf(s[14], s[15]));
        float mt = fmaxf(fmaxf(m0, m1), fmaxf(m2, m3));
        mt = fmaxf(mt, __shfl_xor(mt, 32, 64));
        if (!__all(mt <= mrun + 8.f)) {  // defer-max (T13)
          float mn = fmaxf(mrun, mt);
          float al = __expf(mrun - mn);
          mrun = mn;
          lrun *= al;
#pragma unroll
          for (int hb = 0; hb < 4; hb++)
#pragma unroll
            for (int r = 0; r < 16; r++) o[hb][r] *= al;
        }
        float p[16], ls = 0.f;
#pragma unroll
        for (int r = 0; r < 16; r++) {
          p[r] = __expf(s[r] - mrun);
          ls += p[r];
        }
        ls += __shfl_xor(ls, 32, 64);
        lrun += ls;
        unsigned c0 = cvt_pk_bf16(p[0], p[1]),   c1 = cvt_pk_bf16(p[2], p[3]);
        unsigned c2 = cvt_pk_bf16(p[4], p[5]),   c3 = cvt_pk_bf16(p[6], p[7]);
        unsigned c4 = cvt_pk_bf16(p[8], p[9]),   c5 = cvt_pk_bf16(p[10], p[11]);
        unsigned c6 = cvt_pk_bf16(p[12], p[13]), c7 = cvt_pk_bf16(p[14], p[15]);
        unsigned e0 = (unsigned)__shfl_xor((int)(hi ? c0 : c2), 32, 64);
        unsigned e1 = (unsigned)__shfl_xor((int)(hi ? c1 : c3), 32, 64);
        unsigned e2 = (unsigned)__shfl_xor((int)(hi ? c4 : c6), 32, 64);
        unsigned e3 = (unsigned)__shfl_xor((int)(hi ? c5 : c7), 32, 64);
        union { unsigned u[4]; bf16x8 v; } pb0, pb1;
        pb0.u[0] = hi ? e0 : c0; pb0.u[1] = hi ? e1 : c1;
        pb0.u[2] = hi ? c2 : e0; pb0.u[3] = hi ? c3 : e1;
        pb1.u[0] = hi ? e2 : c4; pb1.u[1] = hi ? e3 : c5;
        pb1.u[2] = hi ? c6 : e2; pb1.u[3] = hi ? c7 : e3;
#pragma unroll
        for (int hb = 0; hb < 4; hb++) {
          const char* Vrow = Vc + (hb * 32 + q31) * 128;
          bf16x8 v0 = *(const bf16x8*)(Vrow + ((kloc2 * 2 + hi * 16) ^ ksw));
          bf16x8 v1 = *(const bf16x8*)(Vrow + ((kloc2 * 2 + 32 + hi * 16) ^ ksw));
          o[hb] = __builtin_amdgcn_mfma_f32_32x32x16_bf16(v0, pb0.v, o[hb], 0, 0, 0);
          o[hb] = __builtin_amdgcn_mfma_f32_32x32x16_bf16(v1, pb1.v, o[hb], 0, 0, 0);
        }
      }
    }
  }
#undef STAGE

  int qtile = (j << 2) + w;
  int slot = (((b << 7) + qtile) << 2) + c;
  float* pob = po + ((size_t)slot << 12);
#pragma unroll
  for (int hb = 0; hb < 4; hb++)
#pragma unroll
    for (int rq = 0; rq < 4; rq++) {
      float4 v;
      v.x = o[hb][rq * 4 + 0];
      v.y = o[hb][rq * 4 + 1];
      v.z = o[hb][rq * 4 + 2];
      v.w = o[hb][rq * 4 + 3];
      *(float4*)&pob[q31 * 128 + 32 * hb + 8 * rq + 4 * hi] = v;
    }
  if (lane < 32) {
    pm[slot * 32 + q31] = mrun;
    pl[slot * 32 + q31] = lrun;
  }
}

// ---------------------------------------------------------------------------
// Combine partials: per (b, q-tile), merge <=4 chunks with rescale, normalize.
// ---------------------------------------------------------------------------
__global__ __launch_bounds__(256) void combine(
    const float* __restrict__ po, const float* __restrict__ pm,
    const float* __restrict__ pl, float* __restrict__ out) {
  int bid = blockIdx.x;  // b*128 + t
  int b = bid >> 7, t = bid & 127;
  int nc = (((t + 1) << 5) + 1023) >> 10;
  int tid = threadIdx.x;
  int row = tid >> 3;
  int hb = (tid & 7) << 4;
  int base = bid * 4;

  float M = -1e30f;
  for (int ci = 0; ci < nc; ci++) M = fmaxf(M, pm[(base + ci) * 32 + row]);
  float L = 0.f;
  float a[16];
#pragma unroll
  for (int j = 0; j < 16; j++) a[j] = 0.f;
  for (int ci = 0; ci < nc; ci++) {
    int sl = base + ci;
    float wgt = __expf(pm[sl * 32 + row] - M);
    L += pl[sl * 32 + row] * wgt;
    const float* p = po + ((size_t)sl << 12) + row * 128 + hb;
#pragma unroll
    for (int j = 0; j < 4; j++) {
      float4 v = *(const float4*)(p + j * 4);
      a[j * 4 + 0] += v.x * wgt;
      a[j * 4 + 1] += v.y * wgt;
      a[j * 4 + 2] += v.z * wgt;
      a[j * 4 + 3] += v.w * wgt;
    }
  }
  float inv = 1.f / L;
  float* ob = out + ((size_t)((b << 12) + (t << 5) + row)) * 128 + hb;
#pragma unroll
  for (int j = 0; j < 16; j++) ob[j] = a[j] * inv;
}

extern "C" void kernel_launch(void* const* d_in, const int* in_sizes, int n_in,
                              void* d_out, int out_size, void* d_ws, size_t ws_size,
                              hipStream_t stream) {
  const float* x  = (const float*)d_in[0];
  const float* Wq = (const float*)d_in[1];
  const float* Wk = (const float*)d_in[2];
  const float* Wv = (const float*)d_in[3];

  unsigned short* ws = (unsigned short*)d_ws;
  unsigned short* Wt = ws;                         // [384][2048] bf16 = 1.5 MB
  unsigned short* qo = ws + 786432;                // 4 MB
  unsigned short* ko = qo + (size_t)M_ * H_;       // 4 MB
  unsigned short* vt = ko + (size_t)M_ * H_;       // 4 MB
  float* po = (float*)(vt + (size_t)M_ * H_);      // 33.5 MB
  float* pm = po + (size_t)2048 * 4096;
  float* pl = pm + 2048 * 32;
  float* out = (float*)d_out;

  hipLaunchKernelGGL(wconv, dim3(3072), dim3(256), 0, stream, Wq, Wk, Wv, Wt);
  hipLaunchKernelGGL(qkv_gemm, dim3(256), dim3(512), 0, stream, x, Wt, qo, ko, vt);
  hipLaunchKernelGGL(attn, dim3(320), dim3(256), 0, stream, qo, ko, vt, po, pm, pl);
  hipLaunchKernelGGL(combine, dim3(512), dim3(256), 0, stream, po, pm, pl, out);
}

// Round 6
// 281.422 us; speedup vs baseline: 1.0672x; 1.0672x over previous
//
#include <hip/hip_runtime.h>
#include <hip/hip_bf16.h>

#define B_ 4
#define L_ 4096
#define D_ 2048
#define H_ 128
#define M_ (B_ * L_)  // 16384

typedef __attribute__((ext_vector_type(8))) short bf16x8;
typedef __attribute__((ext_vector_type(4))) float f32x4;
typedef __attribute__((ext_vector_type(16))) float f32x16;

__device__ __forceinline__ unsigned short f2bf(float f) {
  union { float f; unsigned u; } v; v.f = f;
  unsigned r = v.u + 0x7FFFu + ((v.u >> 16) & 1u);
  return (unsigned short)(r >> 16);
}

__device__ __forceinline__ unsigned cvt_pk_bf16(float lo, float hi) {
  unsigned r;
  asm("v_cvt_pk_bf16_f32 %0, %1, %2" : "=v"(r) : "v"(lo), "v"(hi));
  return r;
}

__device__ __forceinline__ void async_copy16(void* lds, const void* gptr) {
  __builtin_amdgcn_global_load_lds(
      (const __attribute__((address_space(1))) unsigned int*)gptr,
      (__attribute__((address_space(3))) unsigned int*)lds, 16, 0, 0);
}

// ---------------------------------------------------------------------------
// Weight convert: Wt[m*128 + n][d] = W_m[d][n] bf16; 1/sqrt(128) into Wq.
// ---------------------------------------------------------------------------
__global__ void wconv(const float* __restrict__ Wq, const float* __restrict__ Wk,
                      const float* __restrict__ Wv, unsigned short* __restrict__ Wt) {
  int i = blockIdx.x * 256 + threadIdx.x;  // 3*128*2048
  int m = i >> 18;
  int rem = i & 262143;
  int n = rem >> 11;
  int d = rem & 2047;
  const float* W = (m == 0) ? Wq : (m == 1 ? Wk : Wv);
  float val = W[(size_t)d * H_ + n];
  if (m == 0) val *= 0.08838834764831845f;
  Wt[(((size_t)(m << 7) + n) << 11) + d] = f2bf(val);
}

// ---------------------------------------------------------------------------
// QKV GEMM, m97 shape: per-matrix 64x128 tile, BK=64, 4 waves (2x2, 32x64
// each), single-buffered 32 KB LDS, 8 global_load_lds + 16 MFMA per
// thread-step. Grid 768 = 256 row-tiles x 3 mats, 3 blocks/CU; XCD-mapped so
// the 3 mats of a row-tile share an XCD's L2 for the x re-read.
// ---------------------------------------------------------------------------
__global__ __launch_bounds__(256, 4) void qkv_gemm(
    const float* __restrict__ x, const unsigned short* __restrict__ Wt,
    unsigned short* __restrict__ qo, unsigned short* __restrict__ ko,
    unsigned short* __restrict__ vt) {
  __shared__ __align__(16) char Sm[32768];
  char* Ab = Sm;          // fp32 A [64 r][256 B], XOR-swizzled
  char* Bb = Sm + 16384;  // bf16 B [128 r][128 B], XOR-swizzled

  int bid = blockIdx.x;
  int xcd = bid & 7;
  int qq = bid >> 3;
  int mat = qq % 3;
  int rt = (qq / 3) * 8 + xcd;  // row-tile 0..255; same rt for all 3 mats on one XCD
  int row0 = rt * 64;

  int tid = threadIdx.x;
  int lane = tid & 63, w = tid >> 6;
  int wrow = (w >> 1) * 32;
  int wcol = (w & 1) * 64;
  int l15 = lane & 15, lhi = lane >> 4;

  f32x4 zero = {0.f, 0.f, 0.f, 0.f};
  f32x4 acc[2][4];
#pragma unroll
  for (int i = 0; i < 2; i++)
#pragma unroll
    for (int j = 0; j < 4; j++) acc[i][j] = zero;

  const char* xg = (const char*)x;
  const char* wg = (const char*)(Wt + ((size_t)mat << 7) * D_);

  for (int t = 0; t < 32; t++) {
    int k0 = t * 64;
    // stage A: 16 KB fp32 (64 rows x 256 B), linear LDS, inv-swizzled source
#pragma unroll
    for (int p = 0; p < 4; p++) {
      int o = (p * 256 + tid) * 16;
      int r = o >> 8;
      int cb = (o & 255) ^ ((r & 7) << 4);
      async_copy16(Ab + o, xg + (((size_t)(row0 + r) * D_ + k0) << 2) + cb);
    }
    // stage B: 16 KB bf16 (128 rows x 128 B)
#pragma unroll
    for (int p = 0; p < 4; p++) {
      int o = (p * 256 + tid) * 16;
      int r = o >> 7;
      int cb = (o & 127) ^ ((r & 7) << 4);
      async_copy16(Bb + o, wg + (((size_t)r * D_ + k0) << 1) + cb);
    }
    __syncthreads();  // compiler emits vmcnt(0) drain; inter-block overlap hides it

#pragma unroll
    for (int ks = 0; ks < 2; ks++) {
      bf16x8 af[2], bfr[4];
#pragma unroll
      for (int mi = 0; mi < 2; mi++) {
        int r = wrow + mi * 16 + l15;
        int sw = (r & 7) << 4;
        int cb = ks * 128 + lhi * 32;
        float4 lo = *(const float4*)(Ab + r * 256 + (cb ^ sw));
        float4 hi = *(const float4*)(Ab + r * 256 + ((cb + 16) ^ sw));
        union { bf16x8 v; unsigned u[4]; } tt;
        tt.u[0] = cvt_pk_bf16(lo.x, lo.y);
        tt.u[1] = cvt_pk_bf16(lo.z, lo.w);
        tt.u[2] = cvt_pk_bf16(hi.x, hi.y);
        tt.u[3] = cvt_pk_bf16(hi.z, hi.w);
        af[mi] = tt.v;
      }
#pragma unroll
      for (int ni = 0; ni < 4; ni++) {
        int r = wcol + ni * 16 + l15;
        int sw = (r & 7) << 4;
        int cb = ks * 64 + lhi * 16;
        bfr[ni] = *(const bf16x8*)(Bb + r * 128 + (cb ^ sw));
      }
#pragma unroll
      for (int mi = 0; mi < 2; mi++)
#pragma unroll
        for (int ni = 0; ni < 4; ni++)
          acc[mi][ni] = __builtin_amdgcn_mfma_f32_16x16x32_bf16(af[mi], bfr[ni], acc[mi][ni], 0, 0, 0);
    }
    __syncthreads();
  }

  if (mat < 2) {
    unsigned short* dst = (mat == 0) ? qo : ko;
#pragma unroll
    for (int mi = 0; mi < 2; mi++)
#pragma unroll
      for (int ni = 0; ni < 4; ni++)
#pragma unroll
        for (int r = 0; r < 4; r++) {
          int m = row0 + wrow + mi * 16 + lhi * 4 + r;
          int cc = wcol + ni * 16 + l15;
          dst[(size_t)m * H_ + cc] = f2bf(acc[mi][ni][r]);
        }
  } else {
    // V: transpose per-wave 32x64 tile via private LDS slice -> vt[B][H][L]
    unsigned short* Tls = (unsigned short*)Sm + w * 2560;  // [64 n][40 (32 m used)]
#pragma unroll
    for (int ni = 0; ni < 4; ni++)
#pragma unroll
      for (int mi = 0; mi < 2; mi++)
#pragma unroll
        for (int r = 0; r < 4; r++)
          Tls[(ni * 16 + l15) * 40 + mi * 16 + lhi * 4 + r] = f2bf(acc[mi][ni][r]);
    // per-wave private region + in-order DS => no barrier needed
    int b = row0 >> 12;
    int Lbase = (row0 & 4095) + wrow;
    int h = wcol + lane;  // 64 h per wave
#pragma unroll
    for (int j = 0; j < 4; j++) {
      bf16x8 v = *(const bf16x8*)&Tls[lane * 40 + j * 8];
      *(bf16x8*)&vt[(((size_t)(b * H_ + h)) << 12) + Lbase + j * 8] = v;
    }
  }
}

// ---------------------------------------------------------------------------
// Flash attention partials. Block = 128 q-rows (4 waves x 32) x 1024-key
// chunk; K/V tiles (64 keys) double-buffered in LDS, shared by all 4 waves.
// Swapped QK^T (32x32 MFMA), in-register softmax.
// Grid 320: (80 heavy-first (j,c) pairs) x 4 batches.
// ---------------------------------------------------------------------------
__global__ __launch_bounds__(256, 2) void attn(
    const unsigned short* __restrict__ q, const unsigned short* __restrict__ k,
    const unsigned short* __restrict__ vt, float* __restrict__ po,
    float* __restrict__ pm, float* __restrict__ pl) {
  __shared__ __align__(16) char Kb[2][16384];  // K tile [64 keys][128 d] bf16, swizzled
  __shared__ __align__(16) char Vb[2][16384];  // V^T tile [128 h][64 keys] bf16, swizzled

  int bid = blockIdx.x;
  int b = bid & 3;
  int p2 = bid >> 2;  // 0..79, heavy-first
  int j, c;
  if (p2 < 32)      { j = 31 - (p2 >> 2);            c = p2 & 3; }
  else if (p2 < 56) { int i = p2 - 32; int d3 = i / 3; j = 23 - d3; c = i - 3 * d3; }
  else if (p2 < 72) { int i = p2 - 56; j = 15 - (i >> 1); c = i & 1; }
  else              { j = 7 - (p2 - 72);             c = 0; }

  int kbase = c << 10;
  int kmax = min((c + 1) << 10, (j + 1) << 7);
  int NT = (kmax - kbase) >> 6;

  int tid = threadIdx.x;
  int w = tid >> 6, lane = tid & 63;
  int q31 = lane & 31, hi = lane >> 5;
  int qw0 = (j << 7) + (w << 5);  // this wave's 32 q-rows
  int kcap = qw0 + 32;

  const unsigned short* qb = q + ((size_t)b << 12) * H_;
  const char* kbyte = (const char*)(k + ((size_t)b << 12) * H_);
  const char* vbyte = (const char*)(vt + ((size_t)b * H_ << 12));

  bf16x8 qf[8];
#pragma unroll
  for (int kk = 0; kk < 8; kk++)
    qf[kk] = *(const bf16x8*)&qb[(size_t)(qw0 + q31) * H_ + kk * 16 + hi * 8];

  f32x16 o[4];
#pragma unroll
  for (int hb = 0; hb < 4; hb++)
#pragma unroll
    for (int r = 0; r < 16; r++) o[hb][r] = 0.f;
  float mrun = -1e30f, lrun = 0.f;

  int ksw = (q31 & 7) << 4;

#define STAGE(bi, k0)                                                          \
  {                                                                            \
    _Pragma("unroll") for (int p = 0; p < 4; p++) {                            \
      int oo = (p * 256 + tid) * 16;                                           \
      int rr = oo >> 8;                                                        \
      int cc = (oo & 255) ^ ((rr & 7) << 4);                                   \
      async_copy16(Kb[bi] + oo, kbyte + (size_t)((k0) + rr) * 256 + cc);       \
    }                                                                          \
    _Pragma("unroll") for (int p = 0; p < 4; p++) {                            \
      int oo = (p * 256 + tid) * 16;                                           \
      int hh = oo >> 7;                                                        \
      int cc = (oo & 127) ^ ((hh & 7) << 4);                                   \
      async_copy16(Vb[bi] + oo, vbyte + (size_t)hh * 8192 + (size_t)(k0) * 2 + cc); \
    }                                                                          \
  }

  STAGE(0, kbase);

  for (int t = 0; t < NT; t++) {
    __syncthreads();  // drains vmcnt(0): buf[t&1] staged; prior ds_reads done
    int k0 = kbase + (t << 6);
    if (t + 1 < NT) STAGE((t + 1) & 1, k0 + 64);
    const char* Kc = Kb[t & 1];
    const char* Vc = Vb[t & 1];

#pragma unroll
    for (int sub = 0; sub < 2; sub++) {
      int k0s = k0 + (sub << 5);
      if (k0s < kcap) {
        int kloc2 = sub << 5;
        const char* Krow = Kc + (kloc2 + q31) * 256;
        f32x16 s;
#pragma unroll
        for (int r = 0; r < 16; r++) s[r] = 0.f;
#pragma unroll
        for (int kk = 0; kk < 8; kk++) {
          bf16x8 kf = *(const bf16x8*)(Krow + ((kk * 32 + hi * 16) ^ ksw));
          s = __builtin_amdgcn_mfma_f32_32x32x16_bf16(kf, qf[kk], s, 0, 0, 0);
        }
        if (k0s == qw0) {
#pragma unroll
          for (int r = 0; r < 16; r++) {
            int kloc = (r & 3) + 8 * (r >> 2) + 4 * hi;
            if (kloc > q31) s[r] = -1e30f;
          }
        }
        float m0 = fmaxf(fmaxf(s[0], s[1]), fmaxf(s[2], s[3]));
        float m1 = fmaxf(fmaxf(s[4], s[5]), fmaxf(s[6], s[7]));
        float m2 = fmaxf(fmaxf(s[8], s[9]), fmaxf(s[10], s[11]));
        float m3 = fmaxf(fmaxf(s[12], s[13]), fmaxf(s[14], s[15]));
        float mt = fmaxf(fmaxf(m0, m1), fmaxf(m2, m3));
        mt = fmaxf(mt, __shfl_xor(mt, 32, 64));
        if (!__all(mt <= mrun + 8.f)) {  // defer-max (T13)
          float mn = fmaxf(mrun, mt);
          float al = __expf(mrun - mn);
          mrun = mn;
          lrun *= al;
#pragma unroll
          for (int hb = 0; hb < 4; hb++)
#pragma unroll
            for (int r = 0; r < 16; r++) o[hb][r] *= al;
        }
        float p[16], ls = 0.f;
#pragma unroll
        for (int r = 0; r < 16; r++) {
          p[r] = __expf(s[r] - mrun);
          ls += p[r];
        }
        ls += __shfl_xor(ls, 32, 64);
        lrun += ls;
        unsigned c0 = cvt_pk_bf16(p[0], p[1]),   c1 = cvt_pk_bf16(p[2], p[3]);
        unsigned c2 = cvt_pk_bf16(p[4], p[5]),   c3 = cvt_pk_bf16(p[6], p[7]);
        unsigned c4 = cvt_pk_bf16(p[8], p[9]),   c5 = cvt_pk_bf16(p[10], p[11]);
        unsigned c6 = cvt_pk_bf16(p[12], p[13]), c7 = cvt_pk_bf16(p[14], p[15]);
        unsigned e0 = (unsigned)__shfl_xor((int)(hi ? c0 : c2), 32, 64);
        unsigned e1 = (unsigned)__shfl_xor((int)(hi ? c1 : c3), 32, 64);
        unsigned e2 = (unsigned)__shfl_xor((int)(hi ? c4 : c6), 32, 64);
        unsigned e3 = (unsigned)__shfl_xor((int)(hi ? c5 : c7), 32, 64);
        union { unsigned u[4]; bf16x8 v; } pb0, pb1;
        pb0.u[0] = hi ? e0 : c0; pb0.u[1] = hi ? e1 : c1;
        pb0.u[2] = hi ? c2 : e0; pb0.u[3] = hi ? c3 : e1;
        pb1.u[0] = hi ? e2 : c4; pb1.u[1] = hi ? e3 : c5;
        pb1.u[2] = hi ? c6 : e2; pb1.u[3] = hi ? c7 : e3;
#pragma unroll
        for (int hb = 0; hb < 4; hb++) {
          const char* Vrow = Vc + (hb * 32 + q31) * 128;
          bf16x8 v0 = *(const bf16x8*)(Vrow + ((kloc2 * 2 + hi * 16) ^ ksw));
          bf16x8 v1 = *(const bf16x8*)(Vrow + ((kloc2 * 2 + 32 + hi * 16) ^ ksw));
          o[hb] = __builtin_amdgcn_mfma_f32_32x32x16_bf16(v0, pb0.v, o[hb], 0, 0, 0);
          o[hb] = __builtin_amdgcn_mfma_f32_32x32x16_bf16(v1, pb1.v, o[hb], 0, 0, 0);
        }
      }
    }
  }
#undef STAGE

  int qtile = (j << 2) + w;
  int slot = (((b << 7) + qtile) << 2) + c;
  float* pob = po + ((size_t)slot << 12);
#pragma unroll
  for (int hb = 0; hb < 4; hb++)
#pragma unroll
    for (int rq = 0; rq < 4; rq++) {
      float4 v;
      v.x = o[hb][rq * 4 + 0];
      v.y = o[hb][rq * 4 + 1];
      v.z = o[hb][rq * 4 + 2];
      v.w = o[hb][rq * 4 + 3];
      *(float4*)&pob[q31 * 128 + 32 * hb + 8 * rq + 4 * hi] = v;
    }
  if (lane < 32) {
    pm[slot * 32 + q31] = mrun;
    pl[slot * 32 + q31] = lrun;
  }
}

// ---------------------------------------------------------------------------
// Combine partials: per (b, q-tile), merge <=4 chunks with rescale, normalize.
// ---------------------------------------------------------------------------
__global__ __launch_bounds__(256) void combine(
    const float* __restrict__ po, const float* __restrict__ pm,
    const float* __restrict__ pl, float* __restrict__ out) {
  int bid = blockIdx.x;  // b*128 + t
  int b = bid >> 7, t = bid & 127;
  int nc = (((t + 1) << 5) + 1023) >> 10;
  int tid = threadIdx.x;
  int row = tid >> 3;
  int hb = (tid & 7) << 4;
  int base = bid * 4;

  float M = -1e30f;
  for (int ci = 0; ci < nc; ci++) M = fmaxf(M, pm[(base + ci) * 32 + row]);
  float L = 0.f;
  float a[16];
#pragma unroll
  for (int j = 0; j < 16; j++) a[j] = 0.f;
  for (int ci = 0; ci < nc; ci++) {
    int sl = base + ci;
    float wgt = __expf(pm[sl * 32 + row] - M);
    L += pl[sl * 32 + row] * wgt;
    const float* p = po + ((size_t)sl << 12) + row * 128 + hb;
#pragma unroll
    for (int j = 0; j < 4; j++) {
      float4 v = *(const float4*)(p + j * 4);
      a[j * 4 + 0] += v.x * wgt;
      a[j * 4 + 1] += v.y * wgt;
      a[j * 4 + 2] += v.z * wgt;
      a[j * 4 + 3] += v.w * wgt;
    }
  }
  float inv = 1.f / L;
  float* ob = out + ((size_t)((b << 12) + (t << 5) + row)) * 128 + hb;
#pragma unroll
  for (int j = 0; j < 16; j++) ob[j] = a[j] * inv;
}

extern "C" void kernel_launch(void* const* d_in, const int* in_sizes, int n_in,
                              void* d_out, int out_size, void* d_ws, size_t ws_size,
                              hipStream_t stream) {
  const float* x  = (const float*)d_in[0];
  const float* Wq = (const float*)d_in[1];
  const float* Wk = (const float*)d_in[2];
  const float* Wv = (const float*)d_in[3];

  unsigned short* ws = (unsigned short*)d_ws;
  unsigned short* Wt = ws;                         // [384][2048] bf16 = 1.5 MB
  unsigned short* qo = ws + 786432;                // 4 MB
  unsigned short* ko = qo + (size_t)M_ * H_;       // 4 MB
  unsigned short* vt = ko + (size_t)M_ * H_;       // 4 MB
  float* po = (float*)(vt + (size_t)M_ * H_);      // 33.5 MB
  float* pm = po + (size_t)2048 * 4096;
  float* pl = pm + 2048 * 32;
  float* out = (float*)d_out;

  hipLaunchKernelGGL(wconv, dim3(3072), dim3(256), 0, stream, Wq, Wk, Wv, Wt);
  hipLaunchKernelGGL(qkv_gemm, dim3(768), dim3(256), 0, stream, x, Wt, qo, ko, vt);
  hipLaunchKernelGGL(attn, dim3(320), dim3(256), 0, stream, qo, ko, vt, po, pm, pl);
  hipLaunchKernelGGL(combine, dim3(512), dim3(256), 0, stream, po, pm, pl, out);
}

// Round 7
// 279.162 us; speedup vs baseline: 1.0759x; 1.0081x over previous
//
#include <hip/hip_runtime.h>
#include <hip/hip_bf16.h>

#define B_ 4
#define L_ 4096
#define D_ 2048
#define H_ 128
#define M_ (B_ * L_)  // 16384

typedef __attribute__((ext_vector_type(8))) short bf16x8;
typedef __attribute__((ext_vector_type(4))) float f32x4;
typedef __attribute__((ext_vector_type(16))) float f32x16;

__device__ __forceinline__ unsigned short f2bf(float f) {
  union { float f; unsigned u; } v; v.f = f;
  unsigned r = v.u + 0x7FFFu + ((v.u >> 16) & 1u);
  return (unsigned short)(r >> 16);
}

__device__ __forceinline__ unsigned cvt_pk_bf16(float lo, float hi) {
  unsigned r;
  asm("v_cvt_pk_bf16_f32 %0, %1, %2" : "=v"(r) : "v"(lo), "v"(hi));
  return r;
}

__device__ __forceinline__ float bf_lo(unsigned u) {
  union { unsigned x; float f; } t; t.x = u << 16; return t.f;
}
__device__ __forceinline__ float bf_hi(unsigned u) {
  union { unsigned x; float f; } t; t.x = u & 0xFFFF0000u; return t.f;
}

__device__ __forceinline__ void async_copy16(void* lds, const void* gptr) {
  __builtin_amdgcn_global_load_lds(
      (const __attribute__((address_space(1))) unsigned int*)gptr,
      (__attribute__((address_space(3))) unsigned int*)lds, 16, 0, 0);
}

// ---------------------------------------------------------------------------
// Weight convert: Wt[m*128 + n][d] = W_m[d][n] bf16; 1/sqrt(128) into Wq.
// ---------------------------------------------------------------------------
__global__ void wconv(const float* __restrict__ Wq, const float* __restrict__ Wk,
                      const float* __restrict__ Wv, unsigned short* __restrict__ Wt) {
  int i = blockIdx.x * 256 + threadIdx.x;  // 3*128*2048
  int m = i >> 18;
  int rem = i & 262143;
  int n = rem >> 11;
  int d = rem & 2047;
  const float* W = (m == 0) ? Wq : (m == 1 ? Wk : Wv);
  float val = W[(size_t)d * H_ + n];
  if (m == 0) val *= 0.08838834764831845f;
  Wt[(((size_t)(m << 7) + n) << 11) + d] = f2bf(val);
}

// ---------------------------------------------------------------------------
// QKV GEMM: 64x128 tile per mat, BK=64, 4 waves, grid 768 (3 blocks/CU).
// A staged via regs->bf16->LDS (T14 issue-early/write-late); B via
// global_load_lds. Double-buffered 48 KB LDS, ONE barrier per K-step.
// ---------------------------------------------------------------------------
__global__ __launch_bounds__(256, 4) void qkv_gemm(
    const float* __restrict__ x, const unsigned short* __restrict__ Wt,
    unsigned short* __restrict__ qo, unsigned short* __restrict__ ko,
    unsigned short* __restrict__ vt) {
  __shared__ __align__(16) char Sm[49152];
  // A: 2 x [64r][128B] bf16 swz; B: 2 x [128r][128B] bf16 swz

  int bid = blockIdx.x;
  int xcd = bid & 7;
  int qq = bid >> 3;
  int mat = qq % 3;
  int rt = (qq / 3) * 8 + xcd;  // same row-tile for all 3 mats on one XCD
  int row0 = rt * 64;

  int tid = threadIdx.x;
  int lane = tid & 63, w = tid >> 6;
  int wrow = (w >> 1) * 32;
  int wcol = (w & 1) * 64;
  int l15 = lane & 15, lhi = lane >> 4;

  f32x4 zero = {0.f, 0.f, 0.f, 0.f};
  f32x4 acc[2][4];
#pragma unroll
  for (int i = 0; i < 2; i++)
#pragma unroll
    for (int j = 0; j < 4; j++) acc[i][j] = zero;

  const char* wg = (const char*)(Wt + ((size_t)mat << 7) * D_);

  // A staging geometry: thread -> (row ar, 16-float k-chunk)
  int ar = tid >> 2;
  int acb = (tid & 3) << 5;  // byte col of 32B bf16 chunk
  int asw = (ar & 7) << 4;
  const float* xga = x + (size_t)(row0 + ar) * D_ + ((tid & 3) << 4);

#define QSTAGE_B(bi, k0)                                                       \
  _Pragma("unroll") for (int p = 0; p < 4; p++) {                              \
    int o = (p * 256 + tid) * 16;                                              \
    int r = o >> 7;                                                            \
    int cb = (o & 127) ^ ((r & 7) << 4);                                       \
    async_copy16(Sm + 16384 + (bi) * 16384 + o,                                \
                 wg + (((size_t)r * D_ + (k0)) << 1) + cb);                    \
  }

  // prologue: stage tile 0
  {
    float4 av[4];
#pragma unroll
    for (int j = 0; j < 4; j++) av[j] = *(const float4*)(xga + j * 4);
    QSTAGE_B(0, 0);
    unsigned u[8];
#pragma unroll
    for (int j = 0; j < 4; j++) {
      u[2 * j] = cvt_pk_bf16(av[j].x, av[j].y);
      u[2 * j + 1] = cvt_pk_bf16(av[j].z, av[j].w);
    }
    char* abase = Sm + ar * 128;
    *(uint4*)(abase + (acb ^ asw)) = make_uint4(u[0], u[1], u[2], u[3]);
    *(uint4*)(abase + ((acb + 16) ^ asw)) = make_uint4(u[4], u[5], u[6], u[7]);
  }
  __syncthreads();

  for (int t = 0; t < 32; t++) {
    int cur = t & 1, nxt = cur ^ 1;
    bool hn = (t < 31);
    float4 av[4];
    if (hn) {
      int k0n = (t + 1) * 64;
#pragma unroll
      for (int j = 0; j < 4; j++) av[j] = *(const float4*)(xga + k0n + j * 4);
      QSTAGE_B(nxt, k0n);
    }
    // compute tile t from buf[cur]
    const char* A = Sm + cur * 8192;
    const char* Bp = Sm + 16384 + cur * 16384;
#pragma unroll
    for (int ks = 0; ks < 2; ks++) {
      bf16x8 af[2], bfr[4];
#pragma unroll
      for (int mi = 0; mi < 2; mi++) {
        int r = wrow + mi * 16 + l15;
        af[mi] = *(const bf16x8*)(A + r * 128 + ((ks * 64 + lhi * 16) ^ ((r & 7) << 4)));
      }
#pragma unroll
      for (int ni = 0; ni < 4; ni++) {
        int r = wcol + ni * 16 + l15;
        bfr[ni] = *(const bf16x8*)(Bp + r * 128 + ((ks * 64 + lhi * 16) ^ ((r & 7) << 4)));
      }
#pragma unroll
      for (int mi = 0; mi < 2; mi++)
#pragma unroll
        for (int ni = 0; ni < 4; ni++)
          acc[mi][ni] = __builtin_amdgcn_mfma_f32_16x16x32_bf16(af[mi], bfr[ni], acc[mi][ni], 0, 0, 0);
    }
    if (hn) {  // write-late: cvt + ds_write A for t+1
      unsigned u[8];
#pragma unroll
      for (int j = 0; j < 4; j++) {
        u[2 * j] = cvt_pk_bf16(av[j].x, av[j].y);
        u[2 * j + 1] = cvt_pk_bf16(av[j].z, av[j].w);
      }
      char* abase = Sm + nxt * 8192 + ar * 128;
      *(uint4*)(abase + (acb ^ asw)) = make_uint4(u[0], u[1], u[2], u[3]);
      *(uint4*)(abase + ((acb + 16) ^ asw)) = make_uint4(u[4], u[5], u[6], u[7]);
    }
    __syncthreads();
  }
#undef QSTAGE_B

  if (mat < 2) {
    unsigned short* dst = (mat == 0) ? qo : ko;
#pragma unroll
    for (int mi = 0; mi < 2; mi++)
#pragma unroll
      for (int ni = 0; ni < 4; ni++)
#pragma unroll
        for (int r = 0; r < 4; r++) {
          int m = row0 + wrow + mi * 16 + lhi * 4 + r;
          int cc = wcol + ni * 16 + l15;
          dst[(size_t)m * H_ + cc] = f2bf(acc[mi][ni][r]);
        }
  } else {
    // V: transpose per-wave 32x64 tile via private LDS slice -> vt[B][H][L]
    unsigned short* Tls = (unsigned short*)Sm + w * 2560;  // [64 n][40]
#pragma unroll
    for (int ni = 0; ni < 4; ni++)
#pragma unroll
      for (int mi = 0; mi < 2; mi++)
#pragma unroll
        for (int r = 0; r < 4; r++)
          Tls[(ni * 16 + l15) * 40 + mi * 16 + lhi * 4 + r] = f2bf(acc[mi][ni][r]);
    int b = row0 >> 12;
    int Lbase = (row0 & 4095) + wrow;
    int h = wcol + lane;
#pragma unroll
    for (int j = 0; j < 4; j++) {
      bf16x8 v = *(const bf16x8*)&Tls[lane * 40 + j * 8];
      *(bf16x8*)&vt[(((size_t)(b * H_ + h)) << 12) + Lbase + j * 8] = v;
    }
  }
}

// ---------------------------------------------------------------------------
// Flash attention partials. Block = 128 q-rows (4 waves x 32) x 512-key
// chunk; K/V 64-key tiles double-buffered in LDS. Swapped QK^T (32x32 MFMA),
// in-register softmax. Grid 576 = 144 (c-major, heavy-j-first) x 4 batches.
// Partials written as bf16.
// ---------------------------------------------------------------------------
__global__ __launch_bounds__(256, 2) void attn(
    const unsigned short* __restrict__ q, const unsigned short* __restrict__ k,
    const unsigned short* __restrict__ vt, unsigned short* __restrict__ po,
    float* __restrict__ pm, float* __restrict__ pl) {
  __shared__ __align__(16) char Kb[2][16384];  // K tile [64 keys][128 d] swz
  __shared__ __align__(16) char Vb[2][16384];  // V^T tile [128 h][64 keys] swz

  int bid = blockIdx.x;
  int b = bid & 3;
  int p = bid >> 2;  // 0..143
  int c = 0;
  while (p >= 32 - 4 * c) { p -= 32 - 4 * c; c++; }
  int j = 31 - p;  // heavy-first within each chunk group

  int kbase = c << 9;
  int kmax = min((c + 1) << 9, (j + 1) << 7);
  int NT = (kmax - kbase + 63) >> 6;

  int tid = threadIdx.x;
  int w = tid >> 6, lane = tid & 63;
  int q31 = lane & 31, hi = lane >> 5;
  int qw0 = (j << 7) + (w << 5);  // this wave's 32 q-rows
  int kcap = qw0 + 32;

  const unsigned short* qb = q + ((size_t)b << 12) * H_;
  const char* kbyte = (const char*)(k + ((size_t)b << 12) * H_);
  const char* vbyte = (const char*)(vt + ((size_t)b * H_ << 12));

  bf16x8 qf[8];
#pragma unroll
  for (int kk = 0; kk < 8; kk++)
    qf[kk] = *(const bf16x8*)&qb[(size_t)(qw0 + q31) * H_ + kk * 16 + hi * 8];

  f32x16 o[4];
#pragma unroll
  for (int hb = 0; hb < 4; hb++)
#pragma unroll
    for (int r = 0; r < 16; r++) o[hb][r] = 0.f;
  float mrun = -1e30f, lrun = 0.f;

  int ksw = (q31 & 7) << 4;

#define STAGE(bi, k0)                                                          \
  {                                                                            \
    _Pragma("unroll") for (int pp = 0; pp < 4; pp++) {                         \
      int oo = (pp * 256 + tid) * 16;                                          \
      int rr = oo >> 8;                                                        \
      int cc = (oo & 255) ^ ((rr & 7) << 4);                                   \
      async_copy16(Kb[bi] + oo, kbyte + (size_t)((k0) + rr) * 256 + cc);       \
    }                                                                          \
    _Pragma("unroll") for (int pp = 0; pp < 4; pp++) {                         \
      int oo = (pp * 256 + tid) * 16;                                          \
      int hh = oo >> 7;                                                        \
      int cc = (oo & 127) ^ ((hh & 7) << 4);                                   \
      async_copy16(Vb[bi] + oo, vbyte + (size_t)hh * 8192 + (size_t)(k0) * 2 + cc); \
    }                                                                          \
  }

  STAGE(0, kbase);

  for (int t = 0; t < NT; t++) {
    __syncthreads();
    int k0 = kbase + (t << 6);
    if (t + 1 < NT) STAGE((t + 1) & 1, k0 + 64);
    const char* Kc = Kb[t & 1];
    const char* Vc = Vb[t & 1];

#pragma unroll
    for (int sub = 0; sub < 2; sub++) {
      int k0s = k0 + (sub << 5);
      if (k0s < kcap) {
        int kloc2 = sub << 5;
        const char* Krow = Kc + (kloc2 + q31) * 256;
        f32x16 s;
#pragma unroll
        for (int r = 0; r < 16; r++) s[r] = 0.f;
#pragma unroll
        for (int kk = 0; kk < 8; kk++) {
          bf16x8 kf = *(const bf16x8*)(Krow + ((kk * 32 + hi * 16) ^ ksw));
          s = __builtin_amdgcn_mfma_f32_32x32x16_bf16(kf, qf[kk], s, 0, 0, 0);
        }
        if (k0s == qw0) {
#pragma unroll
          for (int r = 0; r < 16; r++) {
            int kloc = (r & 3) + 8 * (r >> 2) + 4 * hi;
            if (kloc > q31) s[r] = -1e30f;
          }
        }
        float m0 = fmaxf(fmaxf(s[0], s[1]), fmaxf(s[2], s[3]));
        float m1 = fmaxf(fmaxf(s[4], s[5]), fmaxf(s[6], s[7]));
        float m2 = fmaxf(fmaxf(s[8], s[9]), fmaxf(s[10], s[11]));
        float m3 = fmaxf(fmaxf(s[12], s[13]), fmaxf(s[14], s[15]));
        float mt = fmaxf(fmaxf(m0, m1), fmaxf(m2, m3));
        mt = fmaxf(mt, __shfl_xor(mt, 32, 64));
        if (!__all(mt <= mrun + 8.f)) {  // defer-max (T13)
          float mn = fmaxf(mrun, mt);
          float al = __expf(mrun - mn);
          mrun = mn;
          lrun *= al;
#pragma unroll
          for (int hb = 0; hb < 4; hb++)
#pragma unroll
            for (int r = 0; r < 16; r++) o[hb][r] *= al;
        }
        float pp[16], ls = 0.f;
#pragma unroll
        for (int r = 0; r < 16; r++) {
          pp[r] = __expf(s[r] - mrun);
          ls += pp[r];
        }
        ls += __shfl_xor(ls, 32, 64);
        lrun += ls;
        unsigned c0 = cvt_pk_bf16(pp[0], pp[1]),   c1 = cvt_pk_bf16(pp[2], pp[3]);
        unsigned c2 = cvt_pk_bf16(pp[4], pp[5]),   c3 = cvt_pk_bf16(pp[6], pp[7]);
        unsigned c4 = cvt_pk_bf16(pp[8], pp[9]),   c5 = cvt_pk_bf16(pp[10], pp[11]);
        unsigned c6 = cvt_pk_bf16(pp[12], pp[13]), c7 = cvt_pk_bf16(pp[14], pp[15]);
        unsigned e0 = (unsigned)__shfl_xor((int)(hi ? c0 : c2), 32, 64);
        unsigned e1 = (unsigned)__shfl_xor((int)(hi ? c1 : c3), 32, 64);
        unsigned e2 = (unsigned)__shfl_xor((int)(hi ? c4 : c6), 32, 64);
        unsigned e3 = (unsigned)__shfl_xor((int)(hi ? c5 : c7), 32, 64);
        union { unsigned u[4]; bf16x8 v; } pb0, pb1;
        pb0.u[0] = hi ? e0 : c0; pb0.u[1] = hi ? e1 : c1;
        pb0.u[2] = hi ? c2 : e0; pb0.u[3] = hi ? c3 : e1;
        pb1.u[0] = hi ? e2 : c4; pb1.u[1] = hi ? e3 : c5;
        pb1.u[2] = hi ? c6 : e2; pb1.u[3] = hi ? c7 : e3;
#pragma unroll
        for (int hb = 0; hb < 4; hb++) {
          const char* Vrow = Vc + (hb * 32 + q31) * 128;
          bf16x8 v0 = *(const bf16x8*)(Vrow + ((kloc2 * 2 + hi * 16) ^ ksw));
          bf16x8 v1 = *(const bf16x8*)(Vrow + ((kloc2 * 2 + 32 + hi * 16) ^ ksw));
          o[hb] = __builtin_amdgcn_mfma_f32_32x32x16_bf16(v0, pb0.v, o[hb], 0, 0, 0);
          o[hb] = __builtin_amdgcn_mfma_f32_32x32x16_bf16(v1, pb1.v, o[hb], 0, 0, 0);
        }
      }
    }
  }
#undef STAGE

  // write partials bf16: slot = ((b*128 + qtile)*8 + c), [32 q][128 h]
  int qtile = (j << 2) + w;
  int slot = (((b << 7) + qtile) << 3) + c;
  unsigned short* pob = po + ((size_t)slot << 12);
#pragma unroll
  for (int hb = 0; hb < 4; hb++)
#pragma unroll
    for (int rq = 0; rq < 4; rq++) {
      unsigned u0 = cvt_pk_bf16(o[hb][rq * 4 + 0], o[hb][rq * 4 + 1]);
      unsigned u1 = cvt_pk_bf16(o[hb][rq * 4 + 2], o[hb][rq * 4 + 3]);
      *(uint2*)&pob[q31 * 128 + 32 * hb + 8 * rq + 4 * hi] = make_uint2(u0, u1);
    }
  if (lane < 32) {
    pm[slot * 32 + q31] = mrun;
    pl[slot * 32 + q31] = lrun;
  }
}

// ---------------------------------------------------------------------------
// Combine partials: per (b, q-tile), merge <=8 chunks with rescale, normalize.
// ---------------------------------------------------------------------------
__global__ __launch_bounds__(256) void combine(
    const unsigned short* __restrict__ po, const float* __restrict__ pm,
    const float* __restrict__ pl, float* __restrict__ out) {
  int bid = blockIdx.x;  // b*128 + t
  int b = bid >> 7, t = bid & 127;
  int nc = (t + 16) >> 4;  // ceil((t+1)/16), 1..8
  int tid = threadIdx.x;
  int row = tid >> 3;
  int hb = (tid & 7) << 4;
  int base = bid * 8;

  float M = -1e30f;
  for (int ci = 0; ci < nc; ci++) M = fmaxf(M, pm[(base + ci) * 32 + row]);
  float L = 0.f;
  float a[16];
#pragma unroll
  for (int j = 0; j < 16; j++) a[j] = 0.f;
  for (int ci = 0; ci < nc; ci++) {
    int sl = base + ci;
    float wgt = __expf(pm[sl * 32 + row] - M);
    L += pl[sl * 32 + row] * wgt;
    const unsigned short* p = po + ((size_t)sl << 12) + row * 128 + hb;
    uint4 v0 = *(const uint4*)p;
    uint4 v1 = *(const uint4*)(p + 8);
    unsigned vv[8] = {v0.x, v0.y, v0.z, v0.w, v1.x, v1.y, v1.z, v1.w};
#pragma unroll
    for (int j = 0; j < 8; j++) {
      a[j * 2 + 0] += bf_lo(vv[j]) * wgt;
      a[j * 2 + 1] += bf_hi(vv[j]) * wgt;
    }
  }
  float inv = 1.f / L;
  float* ob = out + ((size_t)((b << 12) + (t << 5) + row)) * 128 + hb;
#pragma unroll
  for (int j = 0; j < 16; j++) ob[j] = a[j] * inv;
}

extern "C" void kernel_launch(void* const* d_in, const int* in_sizes, int n_in,
                              void* d_out, int out_size, void* d_ws, size_t ws_size,
                              hipStream_t stream) {
  const float* x  = (const float*)d_in[0];
  const float* Wq = (const float*)d_in[1];
  const float* Wk = (const float*)d_in[2];
  const float* Wv = (const float*)d_in[3];

  unsigned short* ws = (unsigned short*)d_ws;
  unsigned short* Wt = ws;                         // 1.5 MB
  unsigned short* qo = ws + 786432;                // 4 MB
  unsigned short* ko = qo + (size_t)M_ * H_;       // 4 MB
  unsigned short* vt = ko + (size_t)M_ * H_;       // 4 MB
  unsigned short* po = vt + (size_t)M_ * H_;       // bf16, 4096 slots x 4096 = 33.5 MB
  float* pm = (float*)(po + (size_t)4096 * 4096);  // 0.5 MB
  float* pl = pm + 4096 * 32;                      // 0.5 MB
  float* out = (float*)d_out;

  hipLaunchKernelGGL(wconv, dim3(3072), dim3(256), 0, stream, Wq, Wk, Wv, Wt);
  hipLaunchKernelGGL(qkv_gemm, dim3(768), dim3(256), 0, stream, x, Wt, qo, ko, vt);
  hipLaunchKernelGGL(attn, dim3(576), dim3(256), 0, stream, qo, ko, vt, po, pm, pl);
  hipLaunchKernelGGL(combine, dim3(512), dim3(256), 0, stream, po, pm, pl, out);
}